// Round 7
// baseline (2072.290 us; speedup 1.0000x reference)
//
#include <hip/hip_runtime.h>

// Chamfer distance via MFMA, one pass computing BOTH directions.
// d2(i,j) = xsq_i + ysq_j - 2 x.y packed into one 32x32x16 bf16 MFMA via
// split-bf16 K-slots (verified exact-enough in R6, absmax 0.0):
//   A k0..15 = [xh0,xh1,xh2, xl0,xl1,xl2, xh0,xh1, xh2, xsqh,xsql, 1,1, 0,0,0]
//   B k0..15 = [-2yh0..2,   -2yh0..2,    -2yl0,1, -2yl2, 1,1, ysqh,ysql, 0,0,0]
// R7 vs R6 (51us, MfmaUtil 6%, latency-bound at 2 blocks/CU):
//  - YB 1024->512, RS 4->2, grid 2048: ~5 blocks/CU, LDS 24 KB
//  - tile-PAIR processing: row acc = min3(acc,d0,d1) -> 8 instr/MFMA (was 16)
//    col tree via min3 groups -> 8 (was 15)
//  - ldsy split by kg: contiguous b128 loads (R6: 393K bank conflicts)
//  - per-wave private col slices, plain ds_write (R6: ds_atomic per tile)

typedef __attribute__((ext_vector_type(8))) short bf16x8;
typedef __attribute__((ext_vector_type(16))) float floatx16;

#define BB 16
#define NN 4096
#define T  256
#define NW 4                 // waves per block
#define RS 2                 // 32-row strips per wave
#define XC (NW * RS * 32)    // 256 x per block
#define YB 512               // y per block
#define YT 32
#define NT (YB / YT)         // 16 tiles
#define ONEBF 0x3F80u
#define FINF  0x7f7f7f7fu    // 3.39e38; "+inf" for uint-ordered min

__device__ __forceinline__ unsigned int f2bf(float f) {
    unsigned int u = __float_as_uint(f);
    u += 0x7fffu + ((u >> 16) & 1u);     // RNE to bf16
    return u >> 16;
}
__device__ __forceinline__ float bf2f(unsigned int h) {
    return __uint_as_float(h << 16);
}
__device__ __forceinline__ float tree16(const floatx16& d) {
    float t0 = fminf(fminf(d[0], d[1]), d[2]);      // -> v_min3_f32
    float t1 = fminf(fminf(d[3], d[4]), d[5]);
    float t2 = fminf(fminf(d[6], d[7]), d[8]);
    float t3 = fminf(fminf(d[9], d[10]), d[11]);
    float t4 = fminf(fminf(d[12], d[13]), d[14]);
    float u0 = fminf(fminf(t0, t1), t2);
    float u1 = fminf(fminf(t3, t4), d[15]);
    return fminf(u0, u1);
}

__global__ __launch_bounds__(T, 4) void chamfer_mfma(
    const float* __restrict__ pred,
    const float* __restrict__ target,
    unsigned int* __restrict__ pmin)     // [BB*NN rows | BB*NN cols], 0x7f-set
{
    __shared__ uint4 ldsy[2][YB];            // 16 KiB, [kg][y]
    __shared__ unsigned int colp[NW * YB];   // 8 KiB, per-wave col mins

    const int b     = blockIdx.y;
    const int xbase = blockIdx.x * XC;
    const int ybase = blockIdx.z * YB;
    const float* prd = pred   + (size_t)b * NN * 3;
    const float* tgt = target + (size_t)b * NN * 3;
    const int tid  = threadIdx.x;
    const int lane = tid & 63, w = tid >> 6;
    const int kg   = lane >> 5, m = lane & 31;

    // ---- stage y records (split by kg so B loads are contiguous) ----
    for (int yl = tid; yl < YB; yl += T) {
        const float* yp = tgt + (size_t)(ybase + yl) * 3;
        float y0 = yp[0], y1 = yp[1], y2 = yp[2];
        unsigned int h0 = f2bf(y0), h1 = f2bf(y1), h2 = f2bf(y2);
        unsigned int H0 = f2bf(-2.f * bf2f(h0));
        unsigned int H1 = f2bf(-2.f * bf2f(h1));
        unsigned int H2 = f2bf(-2.f * bf2f(h2));
        unsigned int L0 = f2bf(-2.f * (y0 - bf2f(h0)));
        unsigned int L1 = f2bf(-2.f * (y1 - bf2f(h1)));
        unsigned int L2 = f2bf(-2.f * (y2 - bf2f(h2)));
        float ysq = fmaf(y0, y0, fmaf(y1, y1, y2 * y2));
        unsigned int sh = f2bf(ysq);
        unsigned int sl = f2bf(ysq - bf2f(sh));
        ldsy[0][yl] = make_uint4(H0 | (H1 << 16), H2 | (H0 << 16),
                                 H1 | (H2 << 16), L0 | (L1 << 16));   // k0..7
        ldsy[1][yl] = make_uint4(L2 | (ONEBF << 16), ONEBF | (sh << 16),
                                 sl, 0u);                             // k8..15
    }
    for (int i = tid; i < NW * YB; i += T) colp[i] = FINF;

    // ---- A fragments (persistent, RS strips) — layout verified in R6 ----
    unsigned int av[RS][4];
#pragma unroll
    for (int s = 0; s < RS; ++s) {
        int xi = xbase + w * (RS * 32) + s * 32 + m;
        const float* xp = prd + (size_t)xi * 3;
        float x0 = xp[0], x1 = xp[1], x2 = xp[2];
        unsigned int h0 = f2bf(x0), h1 = f2bf(x1), h2 = f2bf(x2);
        unsigned int L0 = f2bf(x0 - bf2f(h0));
        unsigned int L1 = f2bf(x1 - bf2f(h1));
        unsigned int L2 = f2bf(x2 - bf2f(h2));
        float xsq = fmaf(x0, x0, fmaf(x1, x1, x2 * x2));
        unsigned int sh = f2bf(xsq);
        unsigned int sl = f2bf(xsq - bf2f(sh));
        av[s][0] = kg ? (h2 | (sh << 16))    : (h0 | (h1 << 16));
        av[s][1] = kg ? (sl | (ONEBF << 16)) : (h2 | (L0 << 16));
        av[s][2] = kg ? ONEBF                : (L1 | (L2 << 16));
        av[s][3] = kg ? 0u                   : (h0 | (h1 << 16));
    }
    __syncthreads();

    // ---- main loop: tiles processed in pairs ----
    floatx16 acc[RS];
#pragma unroll
    for (int s = 0; s < RS; ++s)
#pragma unroll
        for (int r = 0; r < 16; ++r) acc[s][r] = 3.402823466e38f;
    floatx16 zacc;
#pragma unroll
    for (int r = 0; r < 16; ++r) zacc[r] = 0.f;

    union U { uint4 q; bf16x8 v; };
    uint4 bc0 = ldsy[kg][m];
    uint4 bc1 = ldsy[kg][YT + m];
    for (int t = 0; t < NT; t += 2) {
        int tn = (t + 2 < NT) ? t + 2 : 0;
        uint4 bn0 = ldsy[kg][tn * YT + m];          // prefetch next pair
        uint4 bn1 = ldsy[kg][(tn + 1) * YT + m];
        U bu0; bu0.q = bc0;
        U bu1; bu1.q = bc1;
        float cp0 = 3.402823466e38f, cp1 = 3.402823466e38f;
#pragma unroll
        for (int s = 0; s < RS; ++s) {
            U au; au.q = make_uint4(av[s][0], av[s][1], av[s][2], av[s][3]);
            floatx16 d0 = __builtin_amdgcn_mfma_f32_32x32x16_bf16(
                au.v, bu0.v, zacc, 0, 0, 0);
            floatx16 d1 = __builtin_amdgcn_mfma_f32_32x32x16_bf16(
                au.v, bu1.v, zacc, 0, 0, 0);
#pragma unroll
            for (int r = 0; r < 16; ++r)
                acc[s][r] = fminf(fminf(acc[s][r], d0[r]), d1[r]);  // min3
            cp0 = fminf(cp0, tree16(d0));
            cp1 = fminf(cp1, tree16(d1));
        }
        cp0 = fminf(cp0, __shfl_xor(cp0, 32, 64));   // merge kg halves
        cp1 = fminf(cp1, __shfl_xor(cp1, 32, 64));
        if (kg == 0) {
            colp[w * YB + t * YT + m]       = __float_as_uint(fmaxf(cp0, 0.f));
            colp[w * YB + (t + 1) * YT + m] = __float_as_uint(fmaxf(cp1, 0.f));
        }
        bc0 = bn0; bc1 = bn1;
    }

    // ---- row epilogue: reduce across 32 col-lanes, then global min ----
#pragma unroll
    for (int s = 0; s < RS; ++s) {
#pragma unroll
        for (int r = 0; r < 16; ++r) {
            float v = acc[s][r];
            v = fminf(v, __shfl_xor(v, 1, 64));
            v = fminf(v, __shfl_xor(v, 2, 64));
            v = fminf(v, __shfl_xor(v, 4, 64));
            v = fminf(v, __shfl_xor(v, 8, 64));
            v = fminf(v, __shfl_xor(v, 16, 64));
            if (m == 0) {
                int row = (r & 3) + 8 * (r >> 2) + 4 * kg;
                int xi  = xbase + w * (RS * 32) + s * 32 + row;
                atomicMin(&pmin[b * NN + xi], __float_as_uint(fmaxf(v, 0.f)));
            }
        }
    }

    // ---- merge per-wave col slices, flush to global ----
    __syncthreads();
    for (int yl = tid; yl < YB; yl += T) {
        unsigned int v = min(min(colp[yl], colp[YB + yl]),
                             min(colp[2 * YB + yl], colp[3 * YB + yl]));
        atomicMin(&pmin[BB * NN + b * NN + ybase + yl], v);
    }
}

#define TOTX (2 * BB * NN)   // 131072

__global__ __launch_bounds__(256) void chamfer_reduce(
    const float* __restrict__ pmin, float* __restrict__ out)
{
    float s = 0.f;
    for (int i = blockIdx.x * 256 + threadIdx.x; i < TOTX; i += gridDim.x * 256)
        s += pmin[i];
#pragma unroll
    for (int off = 32; off > 0; off >>= 1)
        s += __shfl_down(s, off, 64);
    __shared__ float wsum[4];
    if ((threadIdx.x & 63) == 0) wsum[threadIdx.x >> 6] = s;
    __syncthreads();
    if (threadIdx.x == 0) {
        float t = wsum[0] + wsum[1] + wsum[2] + wsum[3];
        atomicAdd(out, t * (1.0f / (BB * NN)));
    }
}

extern "C" void kernel_launch(void* const* d_in, const int* in_sizes, int n_in,
                              void* d_out, int out_size, void* d_ws, size_t ws_size,
                              hipStream_t stream) {
    const float* pred   = (const float*)d_in[0];
    const float* target = (const float*)d_in[1];
    // d_in[2] (batch, int64) ignored: sorted equal-size segments by construction.
    float* out = (float*)d_out;
    unsigned int* pmin = (unsigned int*)d_ws;      // 512 KiB of ws

    hipMemsetAsync(pmin, 0x7f, (size_t)TOTX * sizeof(unsigned int), stream);
    hipMemsetAsync(out, 0, sizeof(float), stream);

    dim3 grid(NN / XC, BB, NN / YB);               // 16 x 16 x 8 = 2048 blocks
    chamfer_mfma<<<grid, T, 0, stream>>>(pred, target, pmin);
    chamfer_reduce<<<128, 256, 0, stream>>>((const float*)pmin, out);
}

// Round 8
// 97.960 us; speedup vs baseline: 21.1544x; 21.1544x over previous
//
#include <hip/hip_runtime.h>

// Chamfer distance via MFMA, one pass computing BOTH directions.
// d2(i,j) = xsq_i + ysq_j - 2 x.y packed into one 32x32x16 bf16 MFMA via
// split-bf16 K-slots (verified exact-enough in R6, absmax 0.0):
//   A k0..15 = [xh0,xh1,xh2, xl0,xl1,xl2, xh0,xh1, xh2, xsqh,xsql, 1,1, 0,0,0]
//   B k0..15 = [-2yh0..2,   -2yh0..2,    -2yl0,1, -2yl2, 1,1, ysqh,ysql, 0,0,0]
//
// R8 = R7 with __launch_bounds__(256,2). R7's (256,4) halved the VGPR cap
// to 128; the compiler responded with a 64-reg file + scratch spill of the
// acc set -> 7.25 GB of scratch traffic, 2 ms (FETCH_SIZE was the tell).
// R6's (256,2) compiled the same working set spill-free at 84 VGPRs.
// Lesson: give this compiler slack; occupancy follows the real VGPR count
// (64/128/256 cliffs), not the launch-bounds hint.

typedef __attribute__((ext_vector_type(8))) short bf16x8;
typedef __attribute__((ext_vector_type(16))) float floatx16;

#define BB 16
#define NN 4096
#define T  256
#define NW 4                 // waves per block
#define RS 2                 // 32-row strips per wave
#define XC (NW * RS * 32)    // 256 x per block
#define YB 512               // y per block
#define YT 32
#define NT (YB / YT)         // 16 tiles
#define ONEBF 0x3F80u
#define FINF  0x7f7f7f7fu    // 3.39e38; "+inf" for uint-ordered min

__device__ __forceinline__ unsigned int f2bf(float f) {
    unsigned int u = __float_as_uint(f);
    u += 0x7fffu + ((u >> 16) & 1u);     // RNE to bf16
    return u >> 16;
}
__device__ __forceinline__ float bf2f(unsigned int h) {
    return __uint_as_float(h << 16);
}
__device__ __forceinline__ float tree16(const floatx16& d) {
    float t0 = fminf(fminf(d[0], d[1]), d[2]);      // -> v_min3_f32
    float t1 = fminf(fminf(d[3], d[4]), d[5]);
    float t2 = fminf(fminf(d[6], d[7]), d[8]);
    float t3 = fminf(fminf(d[9], d[10]), d[11]);
    float t4 = fminf(fminf(d[12], d[13]), d[14]);
    float u0 = fminf(fminf(t0, t1), t2);
    float u1 = fminf(fminf(t3, t4), d[15]);
    return fminf(u0, u1);
}

__global__ __launch_bounds__(T, 2) void chamfer_mfma(
    const float* __restrict__ pred,
    const float* __restrict__ target,
    unsigned int* __restrict__ pmin)     // [BB*NN rows | BB*NN cols], 0x7f-set
{
    __shared__ uint4 ldsy[2][YB];            // 16 KiB, [kg][y]
    __shared__ unsigned int colp[NW * YB];   // 8 KiB, per-wave col mins

    const int b     = blockIdx.y;
    const int xbase = blockIdx.x * XC;
    const int ybase = blockIdx.z * YB;
    const float* prd = pred   + (size_t)b * NN * 3;
    const float* tgt = target + (size_t)b * NN * 3;
    const int tid  = threadIdx.x;
    const int lane = tid & 63, w = tid >> 6;
    const int kg   = lane >> 5, m = lane & 31;

    // ---- stage y records (split by kg so B loads are contiguous) ----
    for (int yl = tid; yl < YB; yl += T) {
        const float* yp = tgt + (size_t)(ybase + yl) * 3;
        float y0 = yp[0], y1 = yp[1], y2 = yp[2];
        unsigned int h0 = f2bf(y0), h1 = f2bf(y1), h2 = f2bf(y2);
        unsigned int H0 = f2bf(-2.f * bf2f(h0));
        unsigned int H1 = f2bf(-2.f * bf2f(h1));
        unsigned int H2 = f2bf(-2.f * bf2f(h2));
        unsigned int L0 = f2bf(-2.f * (y0 - bf2f(h0)));
        unsigned int L1 = f2bf(-2.f * (y1 - bf2f(h1)));
        unsigned int L2 = f2bf(-2.f * (y2 - bf2f(h2)));
        float ysq = fmaf(y0, y0, fmaf(y1, y1, y2 * y2));
        unsigned int sh = f2bf(ysq);
        unsigned int sl = f2bf(ysq - bf2f(sh));
        ldsy[0][yl] = make_uint4(H0 | (H1 << 16), H2 | (H0 << 16),
                                 H1 | (H2 << 16), L0 | (L1 << 16));   // k0..7
        ldsy[1][yl] = make_uint4(L2 | (ONEBF << 16), ONEBF | (sh << 16),
                                 sl, 0u);                             // k8..15
    }
    for (int i = tid; i < NW * YB; i += T) colp[i] = FINF;

    // ---- A fragments (persistent, RS strips) — layout verified in R6 ----
    unsigned int av[RS][4];
#pragma unroll
    for (int s = 0; s < RS; ++s) {
        int xi = xbase + w * (RS * 32) + s * 32 + m;
        const float* xp = prd + (size_t)xi * 3;
        float x0 = xp[0], x1 = xp[1], x2 = xp[2];
        unsigned int h0 = f2bf(x0), h1 = f2bf(x1), h2 = f2bf(x2);
        unsigned int L0 = f2bf(x0 - bf2f(h0));
        unsigned int L1 = f2bf(x1 - bf2f(h1));
        unsigned int L2 = f2bf(x2 - bf2f(h2));
        float xsq = fmaf(x0, x0, fmaf(x1, x1, x2 * x2));
        unsigned int sh = f2bf(xsq);
        unsigned int sl = f2bf(xsq - bf2f(sh));
        av[s][0] = kg ? (h2 | (sh << 16))    : (h0 | (h1 << 16));
        av[s][1] = kg ? (sl | (ONEBF << 16)) : (h2 | (L0 << 16));
        av[s][2] = kg ? ONEBF                : (L1 | (L2 << 16));
        av[s][3] = kg ? 0u                   : (h0 | (h1 << 16));
    }
    __syncthreads();

    // ---- main loop: tiles processed in pairs ----
    floatx16 acc[RS];
#pragma unroll
    for (int s = 0; s < RS; ++s)
#pragma unroll
        for (int r = 0; r < 16; ++r) acc[s][r] = 3.402823466e38f;
    floatx16 zacc;
#pragma unroll
    for (int r = 0; r < 16; ++r) zacc[r] = 0.f;

    union U { uint4 q; bf16x8 v; };
    uint4 bc0 = ldsy[kg][m];
    uint4 bc1 = ldsy[kg][YT + m];
    for (int t = 0; t < NT; t += 2) {
        int tn = (t + 2 < NT) ? t + 2 : 0;
        uint4 bn0 = ldsy[kg][tn * YT + m];          // prefetch next pair
        uint4 bn1 = ldsy[kg][(tn + 1) * YT + m];
        U bu0; bu0.q = bc0;
        U bu1; bu1.q = bc1;
        float cp0 = 3.402823466e38f, cp1 = 3.402823466e38f;
#pragma unroll
        for (int s = 0; s < RS; ++s) {
            U au; au.q = make_uint4(av[s][0], av[s][1], av[s][2], av[s][3]);
            floatx16 d0 = __builtin_amdgcn_mfma_f32_32x32x16_bf16(
                au.v, bu0.v, zacc, 0, 0, 0);
            floatx16 d1 = __builtin_amdgcn_mfma_f32_32x32x16_bf16(
                au.v, bu1.v, zacc, 0, 0, 0);
#pragma unroll
            for (int r = 0; r < 16; ++r)
                acc[s][r] = fminf(fminf(acc[s][r], d0[r]), d1[r]);  // min3
            cp0 = fminf(cp0, tree16(d0));
            cp1 = fminf(cp1, tree16(d1));
        }
        cp0 = fminf(cp0, __shfl_xor(cp0, 32, 64));   // merge kg halves
        cp1 = fminf(cp1, __shfl_xor(cp1, 32, 64));
        if (kg == 0) {
            colp[w * YB + t * YT + m]       = __float_as_uint(fmaxf(cp0, 0.f));
            colp[w * YB + (t + 1) * YT + m] = __float_as_uint(fmaxf(cp1, 0.f));
        }
        bc0 = bn0; bc1 = bn1;
    }

    // ---- row epilogue: reduce across 32 col-lanes, then global min ----
#pragma unroll
    for (int s = 0; s < RS; ++s) {
#pragma unroll
        for (int r = 0; r < 16; ++r) {
            float v = acc[s][r];
            v = fminf(v, __shfl_xor(v, 1, 64));
            v = fminf(v, __shfl_xor(v, 2, 64));
            v = fminf(v, __shfl_xor(v, 4, 64));
            v = fminf(v, __shfl_xor(v, 8, 64));
            v = fminf(v, __shfl_xor(v, 16, 64));
            if (m == 0) {
                int row = (r & 3) + 8 * (r >> 2) + 4 * kg;
                int xi  = xbase + w * (RS * 32) + s * 32 + row;
                atomicMin(&pmin[b * NN + xi], __float_as_uint(fmaxf(v, 0.f)));
            }
        }
    }

    // ---- merge per-wave col slices, flush to global ----
    __syncthreads();
    for (int yl = tid; yl < YB; yl += T) {
        unsigned int v = min(min(colp[yl], colp[YB + yl]),
                             min(colp[2 * YB + yl], colp[3 * YB + yl]));
        atomicMin(&pmin[BB * NN + b * NN + ybase + yl], v);
    }
}

#define TOTX (2 * BB * NN)   // 131072

__global__ __launch_bounds__(256) void chamfer_reduce(
    const float* __restrict__ pmin, float* __restrict__ out)
{
    float s = 0.f;
    for (int i = blockIdx.x * 256 + threadIdx.x; i < TOTX; i += gridDim.x * 256)
        s += pmin[i];
#pragma unroll
    for (int off = 32; off > 0; off >>= 1)
        s += __shfl_down(s, off, 64);
    __shared__ float wsum[4];
    if ((threadIdx.x & 63) == 0) wsum[threadIdx.x >> 6] = s;
    __syncthreads();
    if (threadIdx.x == 0) {
        float t = wsum[0] + wsum[1] + wsum[2] + wsum[3];
        atomicAdd(out, t * (1.0f / (BB * NN)));
    }
}

extern "C" void kernel_launch(void* const* d_in, const int* in_sizes, int n_in,
                              void* d_out, int out_size, void* d_ws, size_t ws_size,
                              hipStream_t stream) {
    const float* pred   = (const float*)d_in[0];
    const float* target = (const float*)d_in[1];
    // d_in[2] (batch, int64) ignored: sorted equal-size segments by construction.
    float* out = (float*)d_out;
    unsigned int* pmin = (unsigned int*)d_ws;      // 512 KiB of ws

    hipMemsetAsync(pmin, 0x7f, (size_t)TOTX * sizeof(unsigned int), stream);
    hipMemsetAsync(out, 0, sizeof(float), stream);

    dim3 grid(NN / XC, BB, NN / YB);               // 16 x 16 x 8 = 2048 blocks
    chamfer_mfma<<<grid, T, 0, stream>>>(pred, target, pmin);
    chamfer_reduce<<<128, 256, 0, stream>>>((const float*)pmin, out);
}